// Round 8
// baseline (174.788 us; speedup 1.0000x reference)
//
#include <hip/hip_runtime.h>
#include <hip/hip_bf16.h>
#include <math.h>

#define Bt 8
#define Ct 64
#define Ht 128
#define Wt 128
#define Ot 64
#define HWt (Ht*Wt)

// tile decomposition: 16 rows x 8 cols per block; band = tile + 2px margin
#define BROWS 20
#define BCOLS 12
#define BPX   240            // BROWS*BCOLS
// LDS map (bytes): band [0,30720) | wOff (phase1) / odm (phase2) overlay [30720, 67584)
#define WBASE_U 15360        // ushort index of wOff region (byte 30720)
#define ODM_B   30720        // odm overlays wOff after phase-1 barrier

typedef __bf16 bf16x8 __attribute__((ext_vector_type(8)));
typedef float  f32x4  __attribute__((ext_vector_type(4)));

// fp32 -> bf16 bits, round-to-nearest-even, integer ops only
__device__ __forceinline__ uint f2bf_bits(float v) {
    uint u = __float_as_uint(v);
    uint lsb = (u >> 16) & 1u;
    return (u + 0x7fffu + lsb) >> 16;
}
__device__ __forceinline__ ushort f2bf(float v) {
    return (ushort)f2bf_bits(v);
}

// swizzled band access: pixel line pIdx (128B), chunkB in {0,16,...,112}
__device__ __forceinline__ uint4 band_read(const ushort* smem, uint pIdx, uint chunkB) {
    uint off = pIdx * 128u + (chunkB ^ ((pIdx & 7u) << 4));
    return *(const uint4*)((const char*)smem + off);
}

// ---------------- prep ---------------- (unchanged, verified)
__global__ __launch_bounds__(256) void prep_kernel(
    const float* __restrict__ x, const float* __restrict__ w_off,
    const float* __restrict__ w_mask, const float* __restrict__ w_dcn,
    ushort* __restrict__ xTb, ushort* __restrict__ wOffB, ushort* __restrict__ wMainB)
{
    int blk = blockIdx.x;
    int t = threadIdx.x;
    if (blk < 1024) {
        __shared__ float L[64][128];
        int b = blk & 7, y = blk >> 3;
        const float* xb = x + (size_t)b * 1048576 + y * 128;
#pragma unroll
        for (int it = 0; it < 8; ++it) {
            int i = it * 256 + t;
            int c = i >> 5, x4 = i & 31;
            *(float4*)&L[c][x4 * 4] = *(const float4*)&xb[(size_t)c * HWt + x4 * 4];
        }
        __syncthreads();
        int px = t >> 1, half = (t & 1) * 32;
        union { ushort u[32]; uint4 q[4]; } pk;
#pragma unroll
        for (int i = 0; i < 32; ++i) pk.u[i] = f2bf(L[half + i][px]);
        uint4* dst = (uint4*)(xTb + ((size_t)(b * 128 + y) * 128 + px) * 64 + half);
        dst[0] = pk.q[0]; dst[1] = pk.q[1]; dst[2] = pk.q[2]; dst[3] = pk.q[3];
    } else {
        int i = (blk - 1024) * 256 + t;
        if (i < 9 * 32 * 64) {
            int c = i & 63, ch = (i >> 6) & 31, k = i >> 11;
            float v = 0.f;
            if (ch < 18)      v = w_off[(ch * 64 + c) * 9 + k];
            else if (ch < 27) v = w_mask[((ch - 18) * 64 + c) * 9 + k];
            wOffB[i] = f2bf(v);
        } else {
            int j = i - 18432;
            if (j < 9 * 64 * 64) {
                int c = j & 63, o = (j >> 6) & 63, k = j >> 12;
                wMainB[j] = f2bf(w_dcn[(o * 64 + c) * 9 + k]);
            }
        }
    }
}

// ---------------- phase-2 tap context ----------------
struct Tap { float w[4]; int pix[4]; uint gof[4]; uint inb; };

__device__ __forceinline__ void tap_ctx(int k, int ry, float cxf, int cq8,
                                        int row0, int col0,
                                        const float* __restrict__ odmRow, Tap& tp) {
    int ky = k / 3, kx = k - ky * 3;
    float dyv = odmRow[k];
    float dxv = odmRow[9 + k];
    float mkv = odmRow[18 + k];
    float py  = (float)(ry + ky - 1) + dyv;
    float pxf = cxf + (float)(kx - 1) + dxv;
    float y0f = floorf(py), x0f = floorf(pxf);
    float wy1 = py - y0f, wy0 = 1.f - wy1;
    float wx1 = pxf - x0f, wx0 = 1.f - wx1;
    bool vy0 = (y0f >= 0.f) && (y0f <= 127.f);
    bool vy1 = (y0f >= -1.f) && (y0f <= 126.f);
    bool vx0 = (x0f >= 0.f) && (x0f <= 127.f);
    bool vx1 = (x0f >= -1.f) && (x0f <= 126.f);
    tp.w[0] = (vy0 && vx0) ? wy0 * wx0 * mkv : 0.f;
    tp.w[1] = (vy0 && vx1) ? wy0 * wx1 * mkv : 0.f;
    tp.w[2] = (vy1 && vx0) ? wy1 * wx0 * mkv : 0.f;
    tp.w[3] = (vy1 && vx1) ? wy1 * wx1 * mkv : 0.f;
    int yi0 = (int)y0f, xi0 = (int)x0f;
    int y0c = min(max(yi0, 0), 127), y1c = min(max(yi0 + 1, 0), 127);
    int x0c = min(max(xi0, 0), 127), x1c = min(max(xi0 + 1, 0), 127);
    int by0 = y0c - row0, by1 = y1c - row0;
    int bx0 = x0c - col0, bx1 = x1c - col0;
    bool ry0 = (unsigned)by0 < (unsigned)BROWS, ry1 = (unsigned)by1 < (unsigned)BROWS;
    bool rx0 = (unsigned)bx0 < (unsigned)BCOLS, rx1 = (unsigned)bx1 < (unsigned)BCOLS;
    tp.inb = (uint)(ry0 && rx0) | ((uint)(ry0 && rx1) << 1)
           | ((uint)(ry1 && rx0) << 2) | ((uint)(ry1 && rx1) << 3);
    tp.pix[0] = by0 * BCOLS + bx0;
    tp.pix[1] = by0 * BCOLS + bx1;
    tp.pix[2] = by1 * BCOLS + bx0;
    tp.pix[3] = by1 * BCOLS + bx1;
    tp.gof[0] = (uint)(((y0c << 7) + x0c) * 64 + cq8);
    tp.gof[1] = (uint)(((y0c << 7) + x1c) * 64 + cq8);
    tp.gof[2] = (uint)(((y1c << 7) + x0c) * 64 + cq8);
    tp.gof[3] = (uint)(((y1c << 7) + x1c) * 64 + cq8);
}

// exact verified fmaf chain (bit-identical numerics)
__device__ __forceinline__ void tap_blend(const Tap& tp, const uint4* D, bf16x8* afr) {
    float w00 = tp.w[0], w01 = tp.w[1], w10 = tp.w[2], w11 = tp.w[3];
#pragma unroll
    for (int ks = 0; ks < 2; ++ks) {
        union { uint4 q; uint u[4]; } v00, v01, v10, v11, wr;
        v00.q = D[0 * 2 + ks];
        v01.q = D[1 * 2 + ks];
        v10.q = D[2 * 2 + ks];
        v11.q = D[3 * 2 + ks];
#pragma unroll
        for (int j = 0; j < 4; ++j) {
            float f00l = __uint_as_float(v00.u[j] << 16);
            float f00h = __uint_as_float(v00.u[j] & 0xffff0000u);
            float f01l = __uint_as_float(v01.u[j] << 16);
            float f01h = __uint_as_float(v01.u[j] & 0xffff0000u);
            float f10l = __uint_as_float(v10.u[j] << 16);
            float f10h = __uint_as_float(v10.u[j] & 0xffff0000u);
            float f11l = __uint_as_float(v11.u[j] << 16);
            float f11h = __uint_as_float(v11.u[j] & 0xffff0000u);
            float vl = w00 * f00l;
            vl = fmaf(w01, f01l, vl); vl = fmaf(w10, f10l, vl); vl = fmaf(w11, f11l, vl);
            float vh = w00 * f00h;
            vh = fmaf(w01, f01h, vh); vh = fmaf(w10, f10h, vh); vh = fmaf(w11, f11h, vh);
            wr.u[j] = (f2bf_bits(vh) << 16) | f2bf_bits(vl);
        }
        afr[ks] = __builtin_bit_cast(bf16x8, wr.q);
    }
}

// ---------------- fused: band-in-LDS offset conv + bilinear sample + MFMA ----------------
// block = one 16x8 pixel tile of one batch image; 512 thr, 8 waves x 16 px.
// Round-7 structure, minus the wS LDS round trip: phase-2 B-fragments are read
// DIRECTLY from global wMainB (74 KB, L2-resident on every XCD via b=blk&7
// affinity). Deletes 72 ds_read_b128/thread (-35% LDS-pipe traffic, the top
// pipe at 37/58 us), both restage barrier-pairs, and the wS region. odm now
// overlays the wOff region after the phase-1 barrier. Bit-identical values
// and MFMA order.
__global__ __launch_bounds__(512, 4) void dcn_fused_kernel(
    const ushort* __restrict__ xTb, const ushort* __restrict__ wOffB,
    const ushort* __restrict__ wMainB, const float* __restrict__ b_off,
    const float* __restrict__ b_mask, const float* __restrict__ b_dcn,
    float* __restrict__ out)
{
    __shared__ ushort smem[33792];               // 67,584 B
    float* odmF = (float*)((char*)smem + ODM_B); // [128][28] f32 (overlay after p1)

    int t = threadIdx.x;
    int blk = blockIdx.x;
    int b = blk & 7;                 // XCD batch affinity
    int tile = blk >> 3;             // 0..127
    int rowBase = (tile >> 4) * 16;  // 8 row-tiles
    int colBase = (tile & 15) * 8;   // 16 col-tiles
    int wv = t >> 6, ln = t & 63;
    int m = ln & 15, cq = ln >> 4;
    int cq8 = cq * 8;
    int prow = 2 * wv + (m >> 3);    // tile-rel row of this lane's pixel
    int pcol = m & 7;                // tile-rel col
    int ry = rowBase + prow;         // image row
    int cx = colBase + pcol;         // image col

    const ushort* xbb = xTb + (size_t)b * 1048576;

    // ---------- stage band (1920 chunks) + wOff (2304 chunks) ----------
#pragma unroll
    for (int it = 0; it < 4; ++it) {
        int j = it * 512 + t;
        if (j < BPX * 8) {
            int pIdx = j >> 3, ch8 = j & 7;
            int br = pIdx / BCOLS, bc = pIdx - br * BCOLS;
            int iy = min(max(rowBase - 2 + br, 0), 127);
            int ix = min(max(colBase - 2 + bc, 0), 127);
            *(uint4*)((char*)smem + pIdx * 128 + ((ch8 * 16) ^ ((pIdx & 7) << 4))) =
                *(const uint4*)&xbb[(size_t)((iy << 7) + ix) * 64 + ch8 * 8];
        }
    }
#pragma unroll
    for (int it = 0; it < 5; ++it) {
        int j = it * 512 + t;
        if (j < 2304) {
            int row = j >> 3, gch = j & 7;
            int col = ((gch + row) & 7) * 8;
            *(uint4*)&smem[WBASE_U + row * 64 + col] = *(const uint4*)&wOffB[(size_t)row * 64 + gch * 8];
        }
    }
    __syncthreads();

    // ---------- phase 1: offset/mask conv (A from band LDS, B from wOff LDS) ----------
    {
        f32x4 acc0 = {0.f, 0.f, 0.f, 0.f};
        f32x4 acc1 = {0.f, 0.f, 0.f, 0.f};
#pragma unroll
        for (int k = 0; k < 9; ++k) {
            int ky = k / 3, kx = k - ky * 3;
            int iyr = prow + ky - 1;
            int ixr = pcol + kx - 1;
            bool ok = ((unsigned)(rowBase + iyr) < 128u) && ((unsigned)(colBase + ixr) < 128u);
            uint pIdx = (uint)((iyr + 2) * BCOLS + (ixr + 2));   // always in-band
            uint4 a0 = band_read(smem, pIdx, cq8 * 2);
            uint4 a1 = band_read(smem, pIdx, cq8 * 2 + 64);
            if (!ok) { a0 = uint4{0u,0u,0u,0u}; a1 = uint4{0u,0u,0u,0u}; }
            int br0 = k * 32 + m;
            int br1 = br0 + 16;
#pragma unroll
            for (int ks = 0; ks < 2; ++ks) {
                bf16x8 afr = __builtin_bit_cast(bf16x8, ks ? a1 : a0);
                int gs = ks * 4 + cq;
                bf16x8 b0 = __builtin_bit_cast(bf16x8,
                    *(const uint4*)&smem[WBASE_U + br0 * 64 + ((gs + br0) & 7) * 8]);
                bf16x8 b1 = __builtin_bit_cast(bf16x8,
                    *(const uint4*)&smem[WBASE_U + br1 * 64 + ((gs + br1) & 7) * 8]);
                acc0 = __builtin_amdgcn_mfma_f32_16x16x32_bf16(afr, b0, acc0, 0, 0, 0);
                acc1 = __builtin_amdgcn_mfma_f32_16x16x32_bf16(afr, b1, acc1, 0, 0, 0);
            }
        }
        __syncthreads();   // ALL waves done reading wOff: odm overlay may be written

        // epilogue -> odm LDS (overlaying wOff region).
        // slots: 0..8 = dy[k], 9..17 = dx[k], 18..26 = mask[k]
        int n = m;
        int pxl = wv * 16 + (cq << 2);
#pragma unroll
        for (int r = 0; r < 4; ++r) {
            int pp = pxl + r;
            odmF[pp * 28 + (n & 1) * 9 + (n >> 1)] = acc0[r] + b_off[n];
            int ch = 16 + n;
            float v1 = acc1[r];
            if (ch < 18) {
                odmF[pp * 28 + (ch & 1) * 9 + (ch >> 1)] = v1 + b_off[ch];
            } else if (ch < 27) {
                float val = v1 + b_mask[ch - 18];
                odmF[pp * 28 + 18 + (ch - 18)] = 1.f / (1.f + __expf(-val));
            }
        }
        __syncthreads();   // odm visible (odm is wave-local, but keep for safety)
    }

    // ---------- phase 2: bilinear sample from band + main MFMA (barrier-free) ----------
    f32x4 acc[4];
#pragma unroll
    for (int i = 0; i < 4; ++i) acc[i] = f32x4{0.f, 0.f, 0.f, 0.f};

    float cxf = (float)cx;
    const float* odmRow = odmF + (wv * 16 + m) * 28;
    const int row0 = rowBase - 2, col0 = colBase - 2;
    const ushort* wmk = wMainB + (size_t)m * 64 + cq8;   // + k*4096 + nt*1024 + ks*32

#pragma unroll
    for (int k = 0; k < 9; ++k) {
        Tap tp;
        tap_ctx(k, ry, cxf, cq8, row0, col0, odmRow, tp);

        uint4 D[8];
#pragma unroll
        for (int c = 0; c < 4; ++c) {
            bool ib = (tp.inb >> c) & 1u;
            uint pS = ib ? (uint)tp.pix[c] : 0u;
            D[c * 2]     = band_read(smem, pS, cq8 * 2);
            D[c * 2 + 1] = band_read(smem, pS, cq8 * 2 + 64);
            if (!ib) {   // rare fallback (~3e-5): same values from global
                D[c * 2]     = *(const uint4*)(xbb + tp.gof[c]);
                D[c * 2 + 1] = *(const uint4*)(xbb + tp.gof[c] + 32);
            }
        }

        bf16x8 afr[2];
        tap_blend(tp, D, afr);

        const ushort* wk = wmk + (size_t)k * 4096;
#pragma unroll
        for (int ks = 0; ks < 2; ++ks) {
#pragma unroll
            for (int nt = 0; nt < 4; ++nt) {
                bf16x8 bb = __builtin_bit_cast(bf16x8,
                    *(const uint4*)(wk + nt * 1024 + ks * 32));
                acc[nt] = __builtin_amdgcn_mfma_f32_16x16x32_bf16(afr[ks], bb, acc[nt], 0, 0, 0);
            }
        }
    }

    // epilogue: float4 stores (C row q = cq*4+r -> tile row 2wv+(cq>>1), col (cq&1)*4+r)
#pragma unroll
    for (int nt = 0; nt < 4; ++nt) {
        int o = nt * 16 + m;
        float bias = b_dcn[o];
        float4 v;
        v.x = acc[nt][0] + bias;
        v.y = acc[nt][1] + bias;
        v.z = acc[nt][2] + bias;
        v.w = acc[nt][3] + bias;
        float* orow = out + ((size_t)(b * 64 + o) << 14)
                    + (rowBase + 2 * wv + (cq >> 1)) * 128 + colBase + (cq & 1) * 4;
        *(float4*)orow = v;
    }
}

extern "C" void kernel_launch(void* const* d_in, const int* in_sizes, int n_in,
                              void* d_out, int out_size, void* d_ws, size_t ws_size,
                              hipStream_t stream) {
    const float* x      = (const float*)d_in[0];
    const float* w_off  = (const float*)d_in[1];
    const float* b_off  = (const float*)d_in[2];
    const float* w_mask = (const float*)d_in[3];
    const float* b_mask = (const float*)d_in[4];
    const float* w_dcn  = (const float*)d_in[5];
    const float* b_dcn  = (const float*)d_in[6];
    float* out = (float*)d_out;

    ushort* xTb    = (ushort*)d_ws;                  // 8.4M bf16
    ushort* wOffB  = xTb + (size_t)Bt * HWt * 64;    // 18432
    ushort* wMainB = wOffB + 18432;                  // 36864

    hipLaunchKernelGGL(prep_kernel, dim3(1024 + 216), dim3(256), 0, stream,
                       x, w_off, w_mask, w_dcn, xTb, wOffB, wMainB);
    hipLaunchKernelGGL(dcn_fused_kernel, dim3(1024), dim3(512), 0, stream,
                       xTb, wOffB, wMainB, b_off, b_mask, b_dcn, out);
}

// Round 9
// 146.351 us; speedup vs baseline: 1.1943x; 1.1943x over previous
//
#include <hip/hip_runtime.h>
#include <hip/hip_bf16.h>
#include <math.h>

#define Bt 8
#define Ct 64
#define Ht 128
#define Wt 128
#define Ot 64
#define HWt (Ht*Wt)

// tile decomposition: 16 rows x 8 cols per block; band = tile + 2px margin
#define BROWS 20
#define BCOLS 12
#define BPX   240            // BROWS*BCOLS
// LDS map (bytes): band [0,30720) | wbuf 8192 [30720,38912) | odm [38912,52736)
#define WBUF_U 15360         // ushort index of weight buffer (byte 30720)
#define ODM_B  38912
#define ODM_S  27            // odm stride in floats: gcd(27,32)=1 -> conflict-free

typedef __bf16 bf16x8 __attribute__((ext_vector_type(8)));
typedef float  f32x4  __attribute__((ext_vector_type(4)));

// fp32 -> bf16 bits, round-to-nearest-even, integer ops only
__device__ __forceinline__ uint f2bf_bits(float v) {
    uint u = __float_as_uint(v);
    uint lsb = (u >> 16) & 1u;
    return (u + 0x7fffu + lsb) >> 16;
}
__device__ __forceinline__ ushort f2bf(float v) {
    return (ushort)f2bf_bits(v);
}

// swizzled band access: pixel line pIdx (128B), chunkB in {0,16,...,112}
__device__ __forceinline__ uint4 band_read(const ushort* smem, uint pIdx, uint chunkB) {
    uint off = pIdx * 128u + (chunkB ^ ((pIdx & 7u) << 4));
    return *(const uint4*)((const char*)smem + off);
}

// ---------------- prep ---------------- (unchanged, verified)
__global__ __launch_bounds__(256) void prep_kernel(
    const float* __restrict__ x, const float* __restrict__ w_off,
    const float* __restrict__ w_mask, const float* __restrict__ w_dcn,
    ushort* __restrict__ xTb, ushort* __restrict__ wOffB, ushort* __restrict__ wMainB)
{
    int blk = blockIdx.x;
    int t = threadIdx.x;
    if (blk < 1024) {
        __shared__ float L[64][128];
        int b = blk & 7, y = blk >> 3;
        const float* xb = x + (size_t)b * 1048576 + y * 128;
#pragma unroll
        for (int it = 0; it < 8; ++it) {
            int i = it * 256 + t;
            int c = i >> 5, x4 = i & 31;
            *(float4*)&L[c][x4 * 4] = *(const float4*)&xb[(size_t)c * HWt + x4 * 4];
        }
        __syncthreads();
        int px = t >> 1, half = (t & 1) * 32;
        union { ushort u[32]; uint4 q[4]; } pk;
#pragma unroll
        for (int i = 0; i < 32; ++i) pk.u[i] = f2bf(L[half + i][px]);
        uint4* dst = (uint4*)(xTb + ((size_t)(b * 128 + y) * 128 + px) * 64 + half);
        dst[0] = pk.q[0]; dst[1] = pk.q[1]; dst[2] = pk.q[2]; dst[3] = pk.q[3];
    } else {
        int i = (blk - 1024) * 256 + t;
        if (i < 9 * 32 * 64) {
            int c = i & 63, ch = (i >> 6) & 31, k = i >> 11;
            float v = 0.f;
            if (ch < 18)      v = w_off[(ch * 64 + c) * 9 + k];
            else if (ch < 27) v = w_mask[((ch - 18) * 64 + c) * 9 + k];
            wOffB[i] = f2bf(v);
        } else {
            int j = i - 18432;
            if (j < 9 * 64 * 64) {
                int c = j & 63, o = (j >> 6) & 63, k = j >> 12;
                wMainB[j] = f2bf(w_dcn[(o * 64 + c) * 9 + k]);
            }
        }
    }
}

// ---------------- phase-2 tap context ----------------
struct Tap { float w[4]; int pix[4]; uint gof[4]; uint inb; };

__device__ __forceinline__ void tap_ctx(int k, int ry, float cxf, int cq8,
                                        int row0, int col0,
                                        const float* __restrict__ odmRow, Tap& tp) {
    int ky = k / 3, kx = k - ky * 3;
    float dyv = odmRow[k];
    float dxv = odmRow[9 + k];
    float mkv = odmRow[18 + k];
    float py  = (float)(ry + ky - 1) + dyv;
    float pxf = cxf + (float)(kx - 1) + dxv;
    float y0f = floorf(py), x0f = floorf(pxf);
    float wy1 = py - y0f, wy0 = 1.f - wy1;
    float wx1 = pxf - x0f, wx0 = 1.f - wx1;
    bool vy0 = (y0f >= 0.f) && (y0f <= 127.f);
    bool vy1 = (y0f >= -1.f) && (y0f <= 126.f);
    bool vx0 = (x0f >= 0.f) && (x0f <= 127.f);
    bool vx1 = (x0f >= -1.f) && (x0f <= 126.f);
    tp.w[0] = (vy0 && vx0) ? wy0 * wx0 * mkv : 0.f;
    tp.w[1] = (vy0 && vx1) ? wy0 * wx1 * mkv : 0.f;
    tp.w[2] = (vy1 && vx0) ? wy1 * wx0 * mkv : 0.f;
    tp.w[3] = (vy1 && vx1) ? wy1 * wx1 * mkv : 0.f;
    int yi0 = (int)y0f, xi0 = (int)x0f;
    int y0c = min(max(yi0, 0), 127), y1c = min(max(yi0 + 1, 0), 127);
    int x0c = min(max(xi0, 0), 127), x1c = min(max(xi0 + 1, 0), 127);
    int by0 = y0c - row0, by1 = y1c - row0;
    int bx0 = x0c - col0, bx1 = x1c - col0;
    bool ry0 = (unsigned)by0 < (unsigned)BROWS, ry1 = (unsigned)by1 < (unsigned)BROWS;
    bool rx0 = (unsigned)bx0 < (unsigned)BCOLS, rx1 = (unsigned)bx1 < (unsigned)BCOLS;
    tp.inb = (uint)(ry0 && rx0) | ((uint)(ry0 && rx1) << 1)
           | ((uint)(ry1 && rx0) << 2) | ((uint)(ry1 && rx1) << 3);
    tp.pix[0] = by0 * BCOLS + bx0;
    tp.pix[1] = by0 * BCOLS + bx1;
    tp.pix[2] = by1 * BCOLS + bx0;
    tp.pix[3] = by1 * BCOLS + bx1;
    tp.gof[0] = (uint)(((y0c << 7) + x0c) * 64 + cq8);
    tp.gof[1] = (uint)(((y0c << 7) + x1c) * 64 + cq8);
    tp.gof[2] = (uint)(((y1c << 7) + x0c) * 64 + cq8);
    tp.gof[3] = (uint)(((y1c << 7) + x1c) * 64 + cq8);
}

// exact verified fmaf chain (bit-identical numerics)
__device__ __forceinline__ void tap_blend(const Tap& tp, const uint4* D, bf16x8* afr) {
    float w00 = tp.w[0], w01 = tp.w[1], w10 = tp.w[2], w11 = tp.w[3];
#pragma unroll
    for (int ks = 0; ks < 2; ++ks) {
        union { uint4 q; uint u[4]; } v00, v01, v10, v11, wr;
        v00.q = D[0 * 2 + ks];
        v01.q = D[1 * 2 + ks];
        v10.q = D[2 * 2 + ks];
        v11.q = D[3 * 2 + ks];
#pragma unroll
        for (int j = 0; j < 4; ++j) {
            float f00l = __uint_as_float(v00.u[j] << 16);
            float f00h = __uint_as_float(v00.u[j] & 0xffff0000u);
            float f01l = __uint_as_float(v01.u[j] << 16);
            float f01h = __uint_as_float(v01.u[j] & 0xffff0000u);
            float f10l = __uint_as_float(v10.u[j] << 16);
            float f10h = __uint_as_float(v10.u[j] & 0xffff0000u);
            float f11l = __uint_as_float(v11.u[j] << 16);
            float f11h = __uint_as_float(v11.u[j] & 0xffff0000u);
            float vl = w00 * f00l;
            vl = fmaf(w01, f01l, vl); vl = fmaf(w10, f10l, vl); vl = fmaf(w11, f11l, vl);
            float vh = w00 * f00h;
            vh = fmaf(w01, f01h, vh); vh = fmaf(w10, f10h, vh); vh = fmaf(w11, f11h, vh);
            wr.u[j] = (f2bf_bits(vh) << 16) | f2bf_bits(vl);
        }
        afr[ks] = __builtin_bit_cast(bf16x8, wr.q);
    }
}

// ---------------- fused: band-in-LDS offset conv + bilinear sample + MFMA ----------------
// Round-7 structure (all gathers from LDS band — TA-issue fix), re-packed for
// 3 blocks/CU: single 8.2KB weight buffer staged per-2-taps (phase 1) /
// per-tap (phase 2); odm stride 27 (conflict-free). LDS 52,736 B.
__global__ __launch_bounds__(512, 6) void dcn_fused_kernel(
    const ushort* __restrict__ xTb, const ushort* __restrict__ wOffB,
    const ushort* __restrict__ wMainB, const float* __restrict__ b_off,
    const float* __restrict__ b_mask, const float* __restrict__ b_dcn,
    float* __restrict__ out)
{
    __shared__ ushort smem[26368];               // 52,736 B
    float* odmF = (float*)((char*)smem + ODM_B); // [128][27] f32

    int t = threadIdx.x;
    int blk = blockIdx.x;
    int b = blk & 7;                 // XCD batch affinity
    int tile = blk >> 3;             // 0..127
    int rowBase = (tile >> 4) * 16;  // 8 row-tiles
    int colBase = (tile & 15) * 8;   // 16 col-tiles
    int wv = t >> 6, ln = t & 63;
    int m = ln & 15, cq = ln >> 4;
    int cq8 = cq * 8;
    int prow = 2 * wv + (m >> 3);    // tile-rel row of this lane's pixel
    int pcol = m & 7;                // tile-rel col
    int ry = rowBase + prow;         // image row
    int cx = colBase + pcol;         // image col

    const ushort* xbb = xTb + (size_t)b * 1048576;

    // ---------- stage band (1920 chunks) + wOff taps {0,1} (512 chunks) ----------
#pragma unroll
    for (int it = 0; it < 4; ++it) {
        int j = it * 512 + t;
        if (j < BPX * 8) {
            int pIdx = j >> 3, ch8 = j & 7;
            int br = pIdx / BCOLS, bc = pIdx - br * BCOLS;
            int iy = min(max(rowBase - 2 + br, 0), 127);
            int ix = min(max(colBase - 2 + bc, 0), 127);
            *(uint4*)((char*)smem + pIdx * 128 + ((ch8 * 16) ^ ((pIdx & 7) << 4))) =
                *(const uint4*)&xbb[(size_t)((iy << 7) + ix) * 64 + ch8 * 8];
        }
    }
    {
        int r = t >> 3, gch = t & 7;   // rows 0..63 = taps {0,1}
        *(uint4*)&smem[WBUF_U + r * 64 + ((gch + r) & 7) * 8] =
            *(const uint4*)&wOffB[(size_t)r * 64 + gch * 8];
    }
    __syncthreads();

    // ---------- phase 1: offset/mask conv (A from band, B from wbuf 2-tap stages) ----------
    f32x4 acc0 = {0.f, 0.f, 0.f, 0.f};
    f32x4 acc1 = {0.f, 0.f, 0.f, 0.f};
#pragma unroll
    for (int kp = 0; kp < 5; ++kp) {
        if (kp > 0) {
            __syncthreads();   // prior pair's reads done
            const int nchunks = (kp == 4) ? 256 : 512;   // kp=4 stages tap 8 only
            if (t < nchunks) {
                int r = t >> 3, gch = t & 7;
                *(uint4*)&smem[WBUF_U + r * 64 + ((gch + r) & 7) * 8] =
                    *(const uint4*)&wOffB[(size_t)(kp * 64 + r) * 64 + gch * 8];
            }
            __syncthreads();
        }
#pragma unroll
        for (int tl = 0; tl < 2; ++tl) {
            const int k = kp * 2 + tl;
            if (k <= 8) {
                int ky = k / 3, kx = k - ky * 3;
                int iyr = prow + ky - 1;
                int ixr = pcol + kx - 1;
                bool ok = ((unsigned)(rowBase + iyr) < 128u) && ((unsigned)(colBase + ixr) < 128u);
                uint pIdx = (uint)((iyr + 2) * BCOLS + (ixr + 2));   // always in-band
                uint4 a0 = band_read(smem, pIdx, cq8 * 2);
                uint4 a1 = band_read(smem, pIdx, cq8 * 2 + 64);
                if (!ok) { a0 = uint4{0u,0u,0u,0u}; a1 = uint4{0u,0u,0u,0u}; }
                int lbr0 = tl * 32 + m;
                int lbr1 = lbr0 + 16;
#pragma unroll
                for (int ks = 0; ks < 2; ++ks) {
                    bf16x8 afr = __builtin_bit_cast(bf16x8, ks ? a1 : a0);
                    int gs = ks * 4 + cq;
                    bf16x8 b0 = __builtin_bit_cast(bf16x8,
                        *(const uint4*)&smem[WBUF_U + lbr0 * 64 + ((gs + lbr0) & 7) * 8]);
                    bf16x8 b1 = __builtin_bit_cast(bf16x8,
                        *(const uint4*)&smem[WBUF_U + lbr1 * 64 + ((gs + lbr1) & 7) * 8]);
                    acc0 = __builtin_amdgcn_mfma_f32_16x16x32_bf16(afr, b0, acc0, 0, 0, 0);
                    acc1 = __builtin_amdgcn_mfma_f32_16x16x32_bf16(afr, b1, acc1, 0, 0, 0);
                }
            }
        }
    }

    // epilogue -> odm LDS (region disjoint from wbuf/band; stride 27).
    // slots: 0..8 = dy[k], 9..17 = dx[k], 18..26 = mask[k]
    {
        int n = m;
        int pxl = wv * 16 + (cq << 2);
#pragma unroll
        for (int r = 0; r < 4; ++r) {
            int pp = pxl + r;
            odmF[pp * ODM_S + (n & 1) * 9 + (n >> 1)] = acc0[r] + b_off[n];
            int ch = 16 + n;
            float v1 = acc1[r];
            if (ch < 18) {
                odmF[pp * ODM_S + (ch & 1) * 9 + (ch >> 1)] = v1 + b_off[ch];
            } else if (ch < 27) {
                float val = v1 + b_mask[ch - 18];
                odmF[pp * ODM_S + 18 + (ch - 18)] = 1.f / (1.f + __expf(-val));
            }
        }
    }
    __syncthreads();   // wOff reads done by all waves + odm visible

    // stage wS tap 0
    {
        int r = t >> 3, gch = t & 7;
        *(uint4*)&smem[WBUF_U + r * 64 + ((gch + r) & 7) * 8] =
            *(const uint4*)&wMainB[(size_t)r * 64 + gch * 8];
    }
    __syncthreads();

    // ---------- phase 2: bilinear sample from band + main MFMA (per-tap wS stages) ----------
    f32x4 acc[4];
#pragma unroll
    for (int i = 0; i < 4; ++i) acc[i] = f32x4{0.f, 0.f, 0.f, 0.f};

    float cxf = (float)cx;
    const float* odmRow = odmF + (wv * 16 + m) * ODM_S;
    const int row0 = rowBase - 2, col0 = colBase - 2;

#pragma unroll
    for (int k = 0; k < 9; ++k) {
        if (k > 0) {
            __syncthreads();   // prior tap's wS reads done
            int r = t >> 3, gch = t & 7;
            *(uint4*)&smem[WBUF_U + r * 64 + ((gch + r) & 7) * 8] =
                *(const uint4*)&wMainB[(size_t)(k * 64 + r) * 64 + gch * 8];
            __syncthreads();
        }

        Tap tp;
        tap_ctx(k, ry, cxf, cq8, row0, col0, odmRow, tp);

        uint4 D[8];
#pragma unroll
        for (int c = 0; c < 4; ++c) {
            bool ib = (tp.inb >> c) & 1u;
            uint pS = ib ? (uint)tp.pix[c] : 0u;
            D[c * 2]     = band_read(smem, pS, cq8 * 2);
            D[c * 2 + 1] = band_read(smem, pS, cq8 * 2 + 64);
            if (!ib) {   // rare fallback (~3e-5): same values from global
                D[c * 2]     = *(const uint4*)(xbb + tp.gof[c]);
                D[c * 2 + 1] = *(const uint4*)(xbb + tp.gof[c] + 32);
            }
        }

        bf16x8 afr[2];
        tap_blend(tp, D, afr);

#pragma unroll
        for (int ks = 0; ks < 2; ++ks) {
            int chk = ks * 4 + cq;
#pragma unroll
            for (int nt = 0; nt < 4; ++nt) {
                int lrow = nt * 16 + m;
                bf16x8 bb = __builtin_bit_cast(bf16x8,
                    *(const uint4*)&smem[WBUF_U + lrow * 64 + ((chk + lrow) & 7) * 8]);
                acc[nt] = __builtin_amdgcn_mfma_f32_16x16x32_bf16(afr[ks], bb, acc[nt], 0, 0, 0);
            }
        }
    }

    // epilogue: float4 stores (C row q = cq*4+r -> tile row 2wv+(cq>>1), col (cq&1)*4+r)
#pragma unroll
    for (int nt = 0; nt < 4; ++nt) {
        int o = nt * 16 + m;
        float bias = b_dcn[o];
        float4 v;
        v.x = acc[nt][0] + bias;
        v.y = acc[nt][1] + bias;
        v.z = acc[nt][2] + bias;
        v.w = acc[nt][3] + bias;
        float* orow = out + ((size_t)(b * 64 + o) << 14)
                    + (rowBase + 2 * wv + (cq >> 1)) * 128 + colBase + (cq & 1) * 4;
        *(float4*)orow = v;
    }
}

extern "C" void kernel_launch(void* const* d_in, const int* in_sizes, int n_in,
                              void* d_out, int out_size, void* d_ws, size_t ws_size,
                              hipStream_t stream) {
    const float* x      = (const float*)d_in[0];
    const float* w_off  = (const float*)d_in[1];
    const float* b_off  = (const float*)d_in[2];
    const float* w_mask = (const float*)d_in[3];
    const float* b_mask = (const float*)d_in[4];
    const float* w_dcn  = (const float*)d_in[5];
    const float* b_dcn  = (const float*)d_in[6];
    float* out = (float*)d_out;

    ushort* xTb    = (ushort*)d_ws;                  // 8.4M bf16
    ushort* wOffB  = xTb + (size_t)Bt * HWt * 64;    // 18432
    ushort* wMainB = wOffB + 18432;                  // 36864

    hipLaunchKernelGGL(prep_kernel, dim3(1024 + 216), dim3(256), 0, stream,
                       x, w_off, w_mask, w_dcn, xTb, wOffB, wMainB);
    hipLaunchKernelGGL(dcn_fused_kernel, dim3(1024), dim3(512), 0, stream,
                       xTb, wOffB, wMainB, b_off, b_mask, b_dcn, out);
}

// Round 10
// 141.924 us; speedup vs baseline: 1.2316x; 1.0312x over previous
//
#include <hip/hip_runtime.h>
#include <hip/hip_bf16.h>
#include <math.h>

#define Bt 8
#define Ct 64
#define Ht 128
#define Wt 128
#define Ot 64
#define HWt (Ht*Wt)

// tile decomposition: 16 rows x 8 cols per block; band = tile + 2px margin
#define BROWS 20
#define BCOLS 12
#define BPX   240            // BROWS*BCOLS
// LDS map (bytes): band [0,30720) | wbuf 8192 [30720,38912) | odm [38912,52736)
#define WBUF_U 15360         // ushort index of weight buffer (byte 30720)
#define ODM_B  38912
#define ODM_S  27            // odm stride in floats

typedef __bf16 bf16x8 __attribute__((ext_vector_type(8)));
typedef float  f32x4  __attribute__((ext_vector_type(4)));

// fp32 -> bf16 bits, round-to-nearest-even, integer ops only
__device__ __forceinline__ uint f2bf_bits(float v) {
    uint u = __float_as_uint(v);
    uint lsb = (u >> 16) & 1u;
    return (u + 0x7fffu + lsb) >> 16;
}
__device__ __forceinline__ ushort f2bf(float v) {
    return (ushort)f2bf_bits(v);
}

// swizzled band access: pixel line pIdx (128B), chunkB in {0,16,...,112}
__device__ __forceinline__ uint4 band_read(const ushort* smem, uint pIdx, uint chunkB) {
    uint off = pIdx * 128u + (chunkB ^ ((pIdx & 7u) << 4));
    return *(const uint4*)((const char*)smem + off);
}

// ---------------- prep: weight reshapes only (216 blocks) ----------------
__global__ __launch_bounds__(256) void prep_kernel(
    const float* __restrict__ w_off, const float* __restrict__ w_mask,
    const float* __restrict__ w_dcn,
    ushort* __restrict__ wOffB, ushort* __restrict__ wMainB)
{
    int i = blockIdx.x * 256 + threadIdx.x;
    if (i < 9 * 32 * 64) {
        int c = i & 63, ch = (i >> 6) & 31, k = i >> 11;
        float v = 0.f;
        if (ch < 18)      v = w_off[(ch * 64 + c) * 9 + k];
        else if (ch < 27) v = w_mask[((ch - 18) * 64 + c) * 9 + k];
        wOffB[i] = f2bf(v);
    } else {
        int j = i - 18432;
        if (j < 9 * 64 * 64) {
            int c = j & 63, o = (j >> 6) & 63, k = j >> 12;
            wMainB[j] = f2bf(w_dcn[(o * 64 + c) * 9 + k]);
        }
    }
}

// ---------------- phase-2 tap context ----------------
struct Tap { float w[4]; int pix[4]; int pixg[4]; uint inb; };

__device__ __forceinline__ void tap_ctx(int k, int ry, float cxf,
                                        int row0, int col0,
                                        const float* __restrict__ odmRow, Tap& tp) {
    int ky = k / 3, kx = k - ky * 3;
    float dyv = odmRow[k];
    float dxv = odmRow[9 + k];
    float mkv = odmRow[18 + k];
    float py  = (float)(ry + ky - 1) + dyv;
    float pxf = cxf + (float)(kx - 1) + dxv;
    float y0f = floorf(py), x0f = floorf(pxf);
    float wy1 = py - y0f, wy0 = 1.f - wy1;
    float wx1 = pxf - x0f, wx0 = 1.f - wx1;
    bool vy0 = (y0f >= 0.f) && (y0f <= 127.f);
    bool vy1 = (y0f >= -1.f) && (y0f <= 126.f);
    bool vx0 = (x0f >= 0.f) && (x0f <= 127.f);
    bool vx1 = (x0f >= -1.f) && (x0f <= 126.f);
    tp.w[0] = (vy0 && vx0) ? wy0 * wx0 * mkv : 0.f;
    tp.w[1] = (vy0 && vx1) ? wy0 * wx1 * mkv : 0.f;
    tp.w[2] = (vy1 && vx0) ? wy1 * wx0 * mkv : 0.f;
    tp.w[3] = (vy1 && vx1) ? wy1 * wx1 * mkv : 0.f;
    int yi0 = (int)y0f, xi0 = (int)x0f;
    int y0c = min(max(yi0, 0), 127), y1c = min(max(yi0 + 1, 0), 127);
    int x0c = min(max(xi0, 0), 127), x1c = min(max(xi0 + 1, 0), 127);
    int by0 = y0c - row0, by1 = y1c - row0;
    int bx0 = x0c - col0, bx1 = x1c - col0;
    bool ry0 = (unsigned)by0 < (unsigned)BROWS, ry1 = (unsigned)by1 < (unsigned)BROWS;
    bool rx0 = (unsigned)bx0 < (unsigned)BCOLS, rx1 = (unsigned)bx1 < (unsigned)BCOLS;
    tp.inb = (uint)(ry0 && rx0) | ((uint)(ry0 && rx1) << 1)
           | ((uint)(ry1 && rx0) << 2) | ((uint)(ry1 && rx1) << 3);
    tp.pix[0] = by0 * BCOLS + bx0;
    tp.pix[1] = by0 * BCOLS + bx1;
    tp.pix[2] = by1 * BCOLS + bx0;
    tp.pix[3] = by1 * BCOLS + bx1;
    tp.pixg[0] = (y0c << 7) + x0c;
    tp.pixg[1] = (y0c << 7) + x1c;
    tp.pixg[2] = (y1c << 7) + x0c;
    tp.pixg[3] = (y1c << 7) + x1c;
}

// exact verified fmaf chain (bit-identical numerics)
__device__ __forceinline__ void tap_blend(const Tap& tp, const uint4* D, bf16x8* afr) {
    float w00 = tp.w[0], w01 = tp.w[1], w10 = tp.w[2], w11 = tp.w[3];
#pragma unroll
    for (int ks = 0; ks < 2; ++ks) {
        union { uint4 q; uint u[4]; } v00, v01, v10, v11, wr;
        v00.q = D[0 * 2 + ks];
        v01.q = D[1 * 2 + ks];
        v10.q = D[2 * 2 + ks];
        v11.q = D[3 * 2 + ks];
#pragma unroll
        for (int j = 0; j < 4; ++j) {
            float f00l = __uint_as_float(v00.u[j] << 16);
            float f00h = __uint_as_float(v00.u[j] & 0xffff0000u);
            float f01l = __uint_as_float(v01.u[j] << 16);
            float f01h = __uint_as_float(v01.u[j] & 0xffff0000u);
            float f10l = __uint_as_float(v10.u[j] << 16);
            float f10h = __uint_as_float(v10.u[j] & 0xffff0000u);
            float f11l = __uint_as_float(v11.u[j] << 16);
            float f11h = __uint_as_float(v11.u[j] & 0xffff0000u);
            float vl = w00 * f00l;
            vl = fmaf(w01, f01l, vl); vl = fmaf(w10, f10l, vl); vl = fmaf(w11, f11l, vl);
            float vh = w00 * f00h;
            vh = fmaf(w01, f01h, vh); vh = fmaf(w10, f10h, vh); vh = fmaf(w11, f11h, vh);
            wr.u[j] = (f2bf_bits(vh) << 16) | f2bf_bits(vl);
        }
        afr[ks] = __builtin_bit_cast(bf16x8, wr.q);
    }
}

// ---------------- fused: direct-NCHW band stage + offset conv + bilinear + MFMA ----------------
// Round-9 structure; band now staged DIRECTLY from x (NCHW f32): per (8ch-group,
// pixel) 8 row-coalesced f32 loads + f2bf pack + swizzled b128 write. Kills the
// prep transpose kernel (33.5MB R + 16.8MB W) and the xTb round trip entirely.
// Same f2bf per element -> bit-identical band values. Rare out-of-band fallback
// re-reads the same channels from x.
__global__ __launch_bounds__(512, 6) void dcn_fused_kernel(
    const float* __restrict__ x, const ushort* __restrict__ wOffB,
    const ushort* __restrict__ wMainB, const float* __restrict__ b_off,
    const float* __restrict__ b_mask, const float* __restrict__ b_dcn,
    float* __restrict__ out)
{
    __shared__ ushort smem[26368];               // 52,736 B
    float* odmF = (float*)((char*)smem + ODM_B); // [128][27] f32

    int t = threadIdx.x;
    int blk = blockIdx.x;
    int b = blk & 7;                 // XCD batch affinity
    int tile = blk >> 3;             // 0..127
    int rowBase = (tile >> 4) * 16;  // 8 row-tiles
    int colBase = (tile & 15) * 8;   // 16 col-tiles
    int wv = t >> 6, ln = t & 63;
    int m = ln & 15, cq = ln >> 4;
    int cq8 = cq * 8;
    int prow = 2 * wv + (m >> 3);    // tile-rel row of this lane's pixel
    int pcol = m & 7;                // tile-rel col
    int ry = rowBase + prow;         // image row
    int cx = colBase + pcol;         // image col

    const float* xbf = x + (size_t)b * 1048576;  // this batch image (NCHW f32)

    // ---------- stage band from x (1920 8ch-groups) + wOff taps {0,1} ----------
#pragma unroll
    for (int it = 0; it < 4; ++it) {
        int j = it * 512 + t;
        if (j < BPX * 8) {
            int ch8 = j / 240;               // 8-channel group 0..7
            int pIdx = j - ch8 * 240;        // 0..239
            int br = pIdx / BCOLS, bc = pIdx - br * BCOLS;
            int iy = min(max(rowBase - 2 + br, 0), 127);
            int ix = min(max(colBase - 2 + bc, 0), 127);
            const float* xs = xbf + (size_t)(ch8 * 8) * HWt + (iy << 7) + ix;
            union { ushort us[8]; uint4 q; } pk;
#pragma unroll
            for (int u = 0; u < 8; ++u) pk.us[u] = f2bf(xs[(size_t)u * HWt]);
            *(uint4*)((char*)smem + pIdx * 128 + ((ch8 * 16) ^ ((pIdx & 7) << 4))) = pk.q;
        }
    }
    {
        int r = t >> 3, gch = t & 7;   // rows 0..63 = taps {0,1}
        *(uint4*)&smem[WBUF_U + r * 64 + ((gch + r) & 7) * 8] =
            *(const uint4*)&wOffB[(size_t)r * 64 + gch * 8];
    }
    __syncthreads();

    // ---------- phase 1: offset/mask conv (A from band, B from wbuf 2-tap stages) ----------
    f32x4 acc0 = {0.f, 0.f, 0.f, 0.f};
    f32x4 acc1 = {0.f, 0.f, 0.f, 0.f};
#pragma unroll
    for (int kp = 0; kp < 5; ++kp) {
        if (kp > 0) {
            __syncthreads();   // prior pair's reads done
            const int nchunks = (kp == 4) ? 256 : 512;   // kp=4 stages tap 8 only
            if (t < nchunks) {
                int r = t >> 3, gch = t & 7;
                *(uint4*)&smem[WBUF_U + r * 64 + ((gch + r) & 7) * 8] =
                    *(const uint4*)&wOffB[(size_t)(kp * 64 + r) * 64 + gch * 8];
            }
            __syncthreads();
        }
#pragma unroll
        for (int tl = 0; tl < 2; ++tl) {
            const int k = kp * 2 + tl;
            if (k <= 8) {
                int ky = k / 3, kx = k - ky * 3;
                int iyr = prow + ky - 1;
                int ixr = pcol + kx - 1;
                bool ok = ((unsigned)(rowBase + iyr) < 128u) && ((unsigned)(colBase + ixr) < 128u);
                uint pIdx = (uint)((iyr + 2) * BCOLS + (ixr + 2));   // always in-band
                uint4 a0 = band_read(smem, pIdx, cq8 * 2);
                uint4 a1 = band_read(smem, pIdx, cq8 * 2 + 64);
                if (!ok) { a0 = uint4{0u,0u,0u,0u}; a1 = uint4{0u,0u,0u,0u}; }
                int lbr0 = tl * 32 + m;
                int lbr1 = lbr0 + 16;
#pragma unroll
                for (int ks = 0; ks < 2; ++ks) {
                    bf16x8 afr = __builtin_bit_cast(bf16x8, ks ? a1 : a0);
                    int gs = ks * 4 + cq;
                    bf16x8 b0 = __builtin_bit_cast(bf16x8,
                        *(const uint4*)&smem[WBUF_U + lbr0 * 64 + ((gs + lbr0) & 7) * 8]);
                    bf16x8 b1 = __builtin_bit_cast(bf16x8,
                        *(const uint4*)&smem[WBUF_U + lbr1 * 64 + ((gs + lbr1) & 7) * 8]);
                    acc0 = __builtin_amdgcn_mfma_f32_16x16x32_bf16(afr, b0, acc0, 0, 0, 0);
                    acc1 = __builtin_amdgcn_mfma_f32_16x16x32_bf16(afr, b1, acc1, 0, 0, 0);
                }
            }
        }
    }

    // epilogue -> odm LDS (stride 27). slots: 0..8 dy, 9..17 dx, 18..26 mask
    {
        int n = m;
        int pxl = wv * 16 + (cq << 2);
#pragma unroll
        for (int r = 0; r < 4; ++r) {
            int pp = pxl + r;
            odmF[pp * ODM_S + (n & 1) * 9 + (n >> 1)] = acc0[r] + b_off[n];
            int ch = 16 + n;
            float v1 = acc1[r];
            if (ch < 18) {
                odmF[pp * ODM_S + (ch & 1) * 9 + (ch >> 1)] = v1 + b_off[ch];
            } else if (ch < 27) {
                float val = v1 + b_mask[ch - 18];
                odmF[pp * ODM_S + 18 + (ch - 18)] = 1.f / (1.f + __expf(-val));
            }
        }
    }
    __syncthreads();   // wOff reads done by all waves + odm visible

    // stage wS tap 0
    {
        int r = t >> 3, gch = t & 7;
        *(uint4*)&smem[WBUF_U + r * 64 + ((gch + r) & 7) * 8] =
            *(const uint4*)&wMainB[(size_t)r * 64 + gch * 8];
    }
    __syncthreads();

    // ---------- phase 2: bilinear sample from band + main MFMA (per-tap wS stages) ----------
    f32x4 acc[4];
#pragma unroll
    for (int i = 0; i < 4; ++i) acc[i] = f32x4{0.f, 0.f, 0.f, 0.f};

    float cxf = (float)cx;
    const float* odmRow = odmF + (wv * 16 + m) * ODM_S;
    const int row0 = rowBase - 2, col0 = colBase - 2;

#pragma unroll
    for (int k = 0; k < 9; ++k) {
        if (k > 0) {
            __syncthreads();   // prior tap's wS reads done
            int r = t >> 3, gch = t & 7;
            *(uint4*)&smem[WBUF_U + r * 64 + ((gch + r) & 7) * 8] =
                *(const uint4*)&wMainB[(size_t)(k * 64 + r) * 64 + gch * 8];
            __syncthreads();
        }

        Tap tp;
        tap_ctx(k, ry, cxf, row0, col0, odmRow, tp);

        uint4 D[8];
#pragma unroll
        for (int c = 0; c < 4; ++c) {
            bool ib = (tp.inb >> c) & 1u;
            uint pS = ib ? (uint)tp.pix[c] : 0u;
            D[c * 2]     = band_read(smem, pS, cq8 * 2);
            D[c * 2 + 1] = band_read(smem, pS, cq8 * 2 + 64);
            if (!ib) {   // rare fallback (~3e-5): same channels from x, same f2bf
#pragma unroll
                for (int ks = 0; ks < 2; ++ks) {
                    const float* xc = xbf + (size_t)(cq8 + ks * 32) * HWt + tp.pixg[c];
                    union { ushort us[8]; uint4 q; } pk;
#pragma unroll
                    for (int u = 0; u < 8; ++u) pk.us[u] = f2bf(xc[(size_t)u * HWt]);
                    D[c * 2 + ks] = pk.q;
                }
            }
        }

        bf16x8 afr[2];
        tap_blend(tp, D, afr);

#pragma unroll
        for (int ks = 0; ks < 2; ++ks) {
            int chk = ks * 4 + cq;
#pragma unroll
            for (int nt = 0; nt < 4; ++nt) {
                int lrow = nt * 16 + m;
                bf16x8 bb = __builtin_bit_cast(bf16x8,
                    *(const uint4*)&smem[WBUF_U + lrow * 64 + ((chk + lrow) & 7) * 8]);
                acc[nt] = __builtin_amdgcn_mfma_f32_16x16x32_bf16(afr[ks], bb, acc[nt], 0, 0, 0);
            }
        }
    }

    // epilogue: float4 stores (C row q = cq*4+r -> tile row 2wv+(cq>>1), col (cq&1)*4+r)
#pragma unroll
    for (int nt = 0; nt < 4; ++nt) {
        int o = nt * 16 + m;
        float bias = b_dcn[o];
        float4 v;
        v.x = acc[nt][0] + bias;
        v.y = acc[nt][1] + bias;
        v.z = acc[nt][2] + bias;
        v.w = acc[nt][3] + bias;
        float* orow = out + ((size_t)(b * 64 + o) << 14)
                    + (rowBase + 2 * wv + (cq >> 1)) * 128 + colBase + (cq & 1) * 4;
        *(float4*)orow = v;
    }
}

extern "C" void kernel_launch(void* const* d_in, const int* in_sizes, int n_in,
                              void* d_out, int out_size, void* d_ws, size_t ws_size,
                              hipStream_t stream) {
    const float* x      = (const float*)d_in[0];
    const float* w_off  = (const float*)d_in[1];
    const float* b_off  = (const float*)d_in[2];
    const float* w_mask = (const float*)d_in[3];
    const float* b_mask = (const float*)d_in[4];
    const float* w_dcn  = (const float*)d_in[5];
    const float* b_dcn  = (const float*)d_in[6];
    float* out = (float*)d_out;

    ushort* wOffB  = (ushort*)d_ws;                  // 18432 bf16
    ushort* wMainB = wOffB + 18432;                  // 36864 bf16

    hipLaunchKernelGGL(prep_kernel, dim3(216), dim3(256), 0, stream,
                       w_off, w_mask, w_dcn, wOffB, wMainB);
    hipLaunchKernelGGL(dcn_fused_kernel, dim3(1024), dim3(512), 0, stream,
                       x, wOffB, wMainB, b_off, b_mask, b_dcn, out);
}